// Round 4
// baseline (235.637 us; speedup 1.0000x reference)
//
#include <hip/hip_runtime.h>

// 8x8 block DCT: C = A * B * A^T per non-overlapping block.
// R2: LDS-staged coalesced stores (two 128-thread half-phases, XOR-swizzle,
//     measured 0 bank conflicts). Nontemporal output stores -> input stays
//     L3-resident (R3 measured FETCH_SIZE = 65.6 MB = half the input).
// R5: pinned C in regs so phase bodies are pure LDS writes (spills gone).
// R6: VGPR_Count was STILL 48 -> compiler serialized the 16 global loads
//     through a tiny register window (~4 KB/wave in flight; latency-bound:
//     VALU 17%, HBM 31%, occ 34%). Fix: issue ALL 16 loads into a pinned
//     f32x4 r[16] BEFORE any compute (16 KB/wave in flight), two-stage
//     M=B*A^T then C=A*M (flat ~100-reg liveness), __launch_bounds__(256,4)
//     -> 128-VGPR cap, no spill, 4 blocks/CU (LDS 128 KiB).

typedef float f32x4 __attribute__((ext_vector_type(4)));

__global__ __launch_bounds__(256, 4) void dct8x8_kernel(const float* __restrict__ x,
                                                        float* __restrict__ out) {
    constexpr float A[8][8] = {
        { 0.35355339059327373f,  0.35355339059327373f,  0.35355339059327373f,  0.35355339059327373f,
          0.35355339059327373f,  0.35355339059327373f,  0.35355339059327373f,  0.35355339059327373f},
        { 0.49039264020161522f,  0.41573480615127262f,  0.27778511650980114f,  0.09754516100806417f,
         -0.09754516100806417f, -0.27778511650980114f, -0.41573480615127262f, -0.49039264020161522f},
        { 0.46193976625564337f,  0.19134171618254492f, -0.19134171618254492f, -0.46193976625564337f,
         -0.46193976625564337f, -0.19134171618254492f,  0.19134171618254492f,  0.46193976625564337f},
        { 0.41573480615127262f, -0.09754516100806417f, -0.49039264020161522f, -0.27778511650980114f,
          0.27778511650980114f,  0.49039264020161522f,  0.09754516100806417f, -0.41573480615127262f},
        { 0.35355339059327373f, -0.35355339059327373f, -0.35355339059327373f,  0.35355339059327373f,
          0.35355339059327373f, -0.35355339059327373f, -0.35355339059327373f,  0.35355339059327373f},
        { 0.27778511650980114f, -0.49039264020161522f,  0.09754516100806417f,  0.41573480615127262f,
         -0.41573480615127262f, -0.09754516100806417f,  0.49039264020161522f, -0.27778511650980114f},
        { 0.19134171618254492f, -0.46193976625564337f,  0.46193976625564337f, -0.19134171618254492f,
         -0.19134171618254492f,  0.46193976625564337f, -0.46193976625564337f,  0.19134171618254492f},
        { 0.09754516100806417f, -0.27778511650980114f,  0.41573480615127262f, -0.49039264020161522f,
          0.49039264020161522f, -0.41573480615127262f,  0.27778511650980114f, -0.09754516100806417f},
    };

    __shared__ f32x4 lds4[2048];  // 32 KiB staging buffer (one half-phase)

    const int tl = threadIdx.x;
    const int t  = blockIdx.x * 256 + tl;

    // t -> (image n, block-row bi, block-col bj); 128x128 blocks per image
    const int n  = t >> 14;
    const int rm = t & 16383;
    const int bi = rm >> 7;
    const int bj = rm & 127;

    const float* src = x + (((size_t)n << 20) + ((size_t)bi << 13) + ((size_t)bj << 3));

    // Issue ALL loads first: 16 x dwordx4 = 16 KB/wave in flight at once.
    f32x4 r[16];
#pragma unroll
    for (int j = 0; j < 8; ++j) {
        r[2 * j]     = *reinterpret_cast<const f32x4*>(src + (size_t)j * 1024);
        r[2 * j + 1] = *reinterpret_cast<const f32x4*>(src + (size_t)j * 1024 + 4);
    }
#pragma unroll
    for (int k = 0; k < 16; ++k) asm volatile("" : "+v"(r[k]));

    // Stage 1: M = B * A^T, row by row (row j of M needs only row j of B).
    float Mt[64];
#pragma unroll
    for (int j = 0; j < 8; ++j) {
        const float b[8] = {r[2*j].x, r[2*j].y, r[2*j].z, r[2*j].w,
                            r[2*j+1].x, r[2*j+1].y, r[2*j+1].z, r[2*j+1].w};
#pragma unroll
        for (int m = 0; m < 8; ++m) {
            float acc = b[0] * A[m][0];
#pragma unroll
            for (int l = 1; l < 8; ++l) acc = fmaf(b[l], A[m][l], acc);
            Mt[j * 8 + m] = acc;
        }
    }

    // Stage 2: C = A * M.
    float c[64];
#pragma unroll
    for (int i = 0; i < 8; ++i) {
#pragma unroll
        for (int m = 0; m < 8; ++m) {
            float acc = A[i][0] * Mt[m];
#pragma unroll
            for (int j = 1; j < 8; ++j) acc = fmaf(A[i][j], Mt[j * 8 + m], acc);
            c[i * 8 + m] = acc;
        }
    }

    // Pin C: keeps load+compute above the phase structure (R2's 48-VGPR
    // sinking serialized half-1 loads behind phase 0 and spilled).
#pragma unroll
    for (int i = 0; i < 64; ++i) asm volatile("" : "+v"(c[i]));

    // Workgroup w owns blocks [w*256, w*256+256) -> output floats [w*16384, ...).
    float* outw = out + ((size_t)blockIdx.x << 14);

    const int half = tl >> 7;   // wave-uniform: waves 0,1 -> half 0; waves 2,3 -> half 1
    const int tr   = tl & 127;  // rank within half

#pragma unroll
    for (int h = 0; h < 2; ++h) {
        if (half == h) {
            // Pure LDS writes (C already in regs), XOR-swizzled.
#pragma unroll
            for (int i = 0; i < 8; ++i) {
                const int f0 = tr * 16 + i * 2;       // logical float4 index
                const int f1 = f0 + 1;
                f32x4 v0; v0.x = c[i*8+0]; v0.y = c[i*8+1]; v0.z = c[i*8+2]; v0.w = c[i*8+3];
                f32x4 v1; v1.x = c[i*8+4]; v1.y = c[i*8+5]; v1.z = c[i*8+6]; v1.w = c[i*8+7];
                lds4[f0 ^ (tr & 15)] = v0;
                lds4[f1 ^ (tr & 15)] = v1;
            }
        }
        __syncthreads();
        // Cooperative coalesced store: 2048 float4 = 32 KiB contiguous,
        // 256 threads x 16 B = 4 KiB per iteration. Nontemporal: output is
        // write-once -> keep it from evicting the L3-resident input.
        f32x4* dst4 = reinterpret_cast<f32x4*>(outw + h * 8192);
#pragma unroll
        for (int s = 0; s < 8; ++s) {
            const int f4 = s * 256 + tl;
            __builtin_nontemporal_store(lds4[f4 ^ ((f4 >> 4) & 15)], dst4 + f4);
        }
        if (h == 0) __syncthreads();  // protect LDS reuse by the second half-phase
    }
}

extern "C" void kernel_launch(void* const* d_in, const int* in_sizes, int n_in,
                              void* d_out, int out_size, void* d_ws, size_t ws_size,
                              hipStream_t stream) {
    const float* x = (const float*)d_in[0];
    float* out = (float*)d_out;

    const int nblocks = out_size / 64;        // 524288
    const int grid = nblocks / 256;           // 2048 workgroups, exact
    dct8x8_kernel<<<grid, 256, 0, stream>>>(x, out);
}